// Round 15
// baseline (237.589 us; speedup 1.0000x reference)
//
#include <hip/hip_runtime.h>
#include <hip/hip_fp16.h>

#define LRELU_SLOPE 0.2f
#define FSTR 68   // padded LDS row stride in floats (64+4)

// ---------------- DPP helpers ----------------
template <int CTRL>
__device__ __forceinline__ float dpp_add(float x) {
    int xi = __float_as_int(x);
    int yi = __builtin_amdgcn_update_dpp(xi, xi, CTRL, 0xF, 0xF, false);
    return x + __int_as_float(yi);
}
__device__ __forceinline__ float reduce16(float t) {
    t = dpp_add<0x128>(t);  // row_ror:8
    t = dpp_add<0x124>(t);  // row_ror:4
    t = dpp_add<0x122>(t);  // row_ror:2
    t = dpp_add<0x121>(t);  // row_ror:1
    return t;
}
__device__ __forceinline__ float reduce_quad(float t) {
    t = dpp_add<0xB1>(t);   // quad_perm [1,0,3,2]
    t = dpp_add<0x4E>(t);   // quad_perm [2,3,0,1]
    return t;
}

__device__ __forceinline__ float4 h4_to_f4(uint2 raw) {
    __half2 h0 = *(__half2*)&raw.x;
    __half2 h1 = *(__half2*)&raw.y;
    float2 a = __half22float2(h0);
    float2 b = __half22float2(h1);
    return make_float4(a.x, a.y, b.x, b.y);
}
__device__ __forceinline__ uint2 f4_to_h4(float4 v) {
    union { __half2 h2[2]; uint2 u; } pk;
    pk.h2[0] = __floats2half2_rn(v.x, v.y);
    pk.h2[1] = __floats2half2_rn(v.z, v.w);
    return pk.u;
}

// ---------------- block-wide exclusive scan helper (256 threads) -------------
__device__ __forceinline__ int block_excl_scan_256(int v, int* block_total) {
    int lane = threadIdx.x & 63;
    int wid  = threadIdx.x >> 6;
    int x = v;
#pragma unroll
    for (int off = 1; off < 64; off <<= 1) {
        int y = __shfl_up(x, off, 64);
        if (lane >= off) x += y;
    }
    __shared__ int wsum[4];
    if (lane == 63) wsum[wid] = x;
    __syncthreads();
    int t0 = wsum[0], t1 = wsum[1], t2 = wsum[2], t3 = wsum[3];
    int wofs = (wid > 0 ? t0 : 0) + (wid > 1 ? t1 : 0) + (wid > 2 ? t2 : 0);
    if (block_total) *block_total = t0 + t1 + t2 + t3;
    return wofs + x - v;  // exclusive
}

// role split for fused kernels: interleave A/B blocks by parity
__device__ __forceinline__ void role_split(int bid, int gA, int gB, bool& isA, int& idx) {
    int m = (gA < gB ? gA : gB) * 2;
    if (bid < m) { isA = (bid & 1) == 0; idx = bid >> 1; }
    else         { isA = (gA > gB);      idx = (m >> 1) + (bid - m); }
}

#define FMA_TILE(accv, fv, w0, w1, w2, w3)                                     \
    accv.x += fv.x * w0.x + fv.y * w1.x + fv.z * w2.x + fv.w * w3.x;           \
    accv.y += fv.x * w0.y + fv.y * w1.y + fv.z * w2.y + fv.w * w3.y;           \
    accv.z += fv.x * w0.z + fv.y * w1.z + fv.z * w2.z + fv.w * w3.z;           \
    accv.w += fv.x * w0.w + fv.y * w1.w + fv.z * w2.w + fv.w * w3.w;

// ---------------- D1: hist  ||  (gemm_in + fsfd layer0 fused, h in LDS) ------
// r12 structure (no spill) + REGISTER PREFETCH of half-1 features: the 4
// float4 rows for half 1 are loaded during half 0's compute (issued after
// the barrier, consumed by ds_write after the next one) — hides the one
// per-block-unique HBM staging round. Weights are L2-hot, not prefetched.
__global__ __launch_bounds__(256) void k_p1_fused(
        const int* __restrict__ dst, int* __restrict__ counts_T, int E, int B1, int NB,
        const float* __restrict__ feat, const float* __restrict__ Win,
        const float* __restrict__ bin,
        const float* __restrict__ Ws0, const float* __restrict__ bs0,
        const float* __restrict__ Wd0, const float* __restrict__ bd0,
        __half* __restrict__ fs_h, float* __restrict__ fd, int n, int g_gemm) {
    __shared__ float WL[64 * 64];         // 16KB: Win half / Ws0 / Wd0
    __shared__ float FL[64 * FSTR];       // feature k-half, later h-tile
    __shared__ int hist[256];
    bool isA; int idx;
    role_split(blockIdx.x, B1, g_gemm, isA, idx);
    if (isA) {
        hist[threadIdx.x] = 0;
        __syncthreads();
        int base = idx * 4096;
        if (base + 4096 <= E) {
            const int4* d4 = (const int4*)(dst + base);
#pragma unroll
            for (int it = 0; it < 4; ++it) {
                int4 q = d4[it * 256 + threadIdx.x];
                atomicAdd(&hist[q.x >> 8], 1);
                atomicAdd(&hist[q.y >> 8], 1);
                atomicAdd(&hist[q.z >> 8], 1);
                atomicAdd(&hist[q.w >> 8], 1);
            }
        } else {
            for (int it = 0; it < 16; ++it) {
                int e = base + it * 256 + threadIdx.x;
                if (e < E) atomicAdd(&hist[dst[e] >> 8], 1);
            }
        }
        __syncthreads();
        if (threadIdx.x < NB) counts_T[threadIdx.x * B1 + idx] = hist[threadIdx.x];
        return;
    }
    int node0 = idx * 64;
    int rows = n - node0; rows = rows < 64 ? rows : 64;
    int ng = threadIdx.x >> 4;        // 0..15 node group
    int cg = (threadIdx.x & 15) * 4;  // col base
    int tn = threadIdx.x >> 4, tf = threadIdx.x & 15;
    float4 acc[4];
    {
        float4 bb = *(const float4*)(bin + cg);
#pragma unroll
        for (int j = 0; j < 4; ++j) acc[j] = bb;
    }
    // clamped staging row ids (branchless; OOB rows carry dup data, never stored)
    const float4* g4 = (const float4*)(feat + (size_t)node0 * 128);
    int ndc[4];
#pragma unroll
    for (int r = 0; r < 4; ++r) {
        int nd = r * 16 + tn;
        ndc[r] = nd < rows ? nd : rows - 1;
    }
    // prefetch half-0 features
    float4 fpre[4];
#pragma unroll
    for (int r = 0; r < 4; ++r)
        fpre[r] = g4[(size_t)ndc[r] * 32 + tf];
    // ---- phase 1: gemm_in, two k-halves; features double-staged via regs ----
#pragma unroll
    for (int hk = 0; hk < 2; ++hk) {
        {   // commit prefetched features to LDS + stage W_in half (L2-hot)
            float4* f4 = (float4*)FL;
#pragma unroll
            for (int r = 0; r < 4; ++r)
                f4[(r * 16 + tn) * (FSTR / 4) + tf] = fpre[r];
            float4* WL4 = (float4*)WL;
            const float4* W4 = (const float4*)(Win + hk * 4096);
#pragma unroll
            for (int r = 0; r < 4; ++r)
                WL4[r * 256 + threadIdx.x] = W4[r * 256 + threadIdx.x];
        }
        __syncthreads();
        if (hk == 0) {   // prefetch half-1 features during half-0 compute
#pragma unroll
            for (int r = 0; r < 4; ++r)
                fpre[r] = g4[(size_t)ndc[r] * 32 + 16 + tf];
        }
#pragma unroll 4
        for (int k4 = 0; k4 < 16; ++k4) {
            float4 f[4];
#pragma unroll
            for (int j = 0; j < 4; ++j)
                f[j] = *(const float4*)(FL + (ng * 4 + j) * FSTR + k4 * 4);
            const float* wp = WL + (k4 * 4) * 64 + cg;
            float4 w0 = *(const float4*)(wp);
            float4 w1 = *(const float4*)(wp + 64);
            float4 w2 = *(const float4*)(wp + 128);
            float4 w3 = *(const float4*)(wp + 192);
#pragma unroll
            for (int j = 0; j < 4; ++j) { FMA_TILE(acc[j], f[j], w0, w1, w2, w3); }
        }
        __syncthreads();  // FL/WL reads done before restage
    }
    // ---- phase 2a: h-tile -> FL; Ws0 -> WL; compute fs0 (store FP16) ---------
#pragma unroll
    for (int j = 0; j < 4; ++j)
        *(float4*)(FL + (ng * 4 + j) * FSTR + cg) = acc[j];
    {
        float4* WL4 = (float4*)WL;
        const float4* W4 = (const float4*)Ws0;
#pragma unroll
        for (int r = 0; r < 4; ++r)
            WL4[r * 256 + threadIdx.x] = W4[r * 256 + threadIdx.x];
    }
    __syncthreads();
    {
        float4 bs4 = *(const float4*)(bs0 + cg);
        float4 aS[4];
#pragma unroll
        for (int j = 0; j < 4; ++j) aS[j] = bs4;
#pragma unroll 4
        for (int k4 = 0; k4 < 16; ++k4) {
            float4 f[4];
#pragma unroll
            for (int j = 0; j < 4; ++j)
                f[j] = *(const float4*)(FL + (ng * 4 + j) * FSTR + k4 * 4);
            const float* wp = WL + (k4 * 4) * 64 + cg;
            float4 w0 = *(const float4*)(wp);
            float4 w1 = *(const float4*)(wp + 64);
            float4 w2 = *(const float4*)(wp + 128);
            float4 w3 = *(const float4*)(wp + 192);
#pragma unroll
            for (int j = 0; j < 4; ++j) { FMA_TILE(aS[j], f[j], w0, w1, w2, w3); }
        }
#pragma unroll
        for (int j = 0; j < 4; ++j) {
            int node = node0 + ng * 4 + j;
            if (node < n)
                *(uint2*)(fs_h + (size_t)node * 64 + cg) = f4_to_h4(aS[j]);
        }
    }
    __syncthreads();
    // ---- phase 2b: Wd0 -> WL; compute fd (FP32) -----------------------------
    {
        float4* WL4 = (float4*)WL;
        const float4* W4 = (const float4*)Wd0;
#pragma unroll
        for (int r = 0; r < 4; ++r)
            WL4[r * 256 + threadIdx.x] = W4[r * 256 + threadIdx.x];
    }
    __syncthreads();
    {
        float4 bd4 = *(const float4*)(bd0 + cg);
        float4 aD[4];
#pragma unroll
        for (int j = 0; j < 4; ++j) aD[j] = bd4;
#pragma unroll 4
        for (int k4 = 0; k4 < 16; ++k4) {
            float4 f[4];
#pragma unroll
            for (int j = 0; j < 4; ++j)
                f[j] = *(const float4*)(FL + (ng * 4 + j) * FSTR + k4 * 4);
            const float* wp = WL + (k4 * 4) * 64 + cg;
            float4 w0 = *(const float4*)(wp);
            float4 w1 = *(const float4*)(wp + 64);
            float4 w2 = *(const float4*)(wp + 128);
            float4 w3 = *(const float4*)(wp + 192);
#pragma unroll
            for (int j = 0; j < 4; ++j) { FMA_TILE(aD[j], f[j], w0, w1, w2, w3); }
        }
#pragma unroll
        for (int j = 0; j < 4; ++j) {
            int node = node0 + ng * 4 + j;
            if (node < n) *(float4*)(fd + (size_t)node * 64 + cg) = aD[j];
        }
    }
}

// ---------------- D2: parallel coarse scan ----------------
__global__ __launch_bounds__(256) void k_scan(
        const int* __restrict__ counts_T, int* __restrict__ off_T,
        int* __restrict__ Ssum, int* __restrict__ row_ptr,
        int* __restrict__ edge_src, int E, int B1, int NB, int n_nodes) {
    int c = blockIdx.x * 4 + (threadIdx.x >> 6);
    int lane = threadIdx.x & 63;
    if (c < NB) {
        int carry = 0;
        for (int b0 = 0; b0 < B1; b0 += 64) {
            int b = b0 + lane;
            int v = (b < B1) ? counts_T[c * B1 + b] : 0;
            int x = v;
#pragma unroll
            for (int o = 1; o < 64; o <<= 1) {
                int y = __shfl_up(x, o, 64);
                if (lane >= o) x += y;
            }
            if (b < B1) off_T[c * B1 + b] = carry + x - v;
            carry += __shfl(x, 63, 64);
        }
        if (lane == 0) Ssum[c] = carry;
    }
    if (blockIdx.x == 0) {
        if (threadIdx.x < 64) edge_src[E + threadIdx.x] = 0;  // pad for k_agg
        if (threadIdx.x == 0) row_ptr[n_nodes] = E;
    }
}

// ---------------- D3: coarse partition, packed 24-bit (src<<8)|fine ----------
__global__ __launch_bounds__(256) void k_p3(
        const int* __restrict__ src, const int* __restrict__ dst,
        const int* __restrict__ off_T, const int* __restrict__ Ssum,
        int* __restrict__ karr, int E, int B1, int NB) {
    __shared__ int cur[256];
    int b = blockIdx.x, t = threadIdx.x;
    int v = (t < NB) ? Ssum[t] : 0;
    int base_t = block_excl_scan_256(v, nullptr);   // bucket_base[t]
    cur[t] = (t < NB) ? base_t + off_T[t * B1 + b] : 0;
    __syncthreads();
    int base = b * 4096;
    if (base + 4096 <= E) {
        const int4* d4 = (const int4*)(dst + base);
        const int4* s4 = (const int4*)(src + base);
#pragma unroll
        for (int it = 0; it < 4; ++it) {
            int4 qd = d4[it * 256 + t];
            int4 qs = s4[it * 256 + t];
            int pos;
            pos = atomicAdd(&cur[qd.x >> 8], 1); karr[pos] = (qs.x << 8) | (qd.x & 255);
            pos = atomicAdd(&cur[qd.y >> 8], 1); karr[pos] = (qs.y << 8) | (qd.y & 255);
            pos = atomicAdd(&cur[qd.z >> 8], 1); karr[pos] = (qs.z << 8) | (qd.z & 255);
            pos = atomicAdd(&cur[qd.w >> 8], 1); karr[pos] = (qs.w << 8) | (qd.w & 255);
        }
    } else {
        for (int it = 0; it < 16; ++it) {
            int e = base + it * 256 + t;
            if (e < E) {
                int d = dst[e], s = src[e];
                int pos = atomicAdd(&cur[d >> 8], 1);  // LDS atomic
                karr[pos] = (s << 8) | (d & 255);
            }
        }
    }
}

// ---------------- D4: fine counting sort, single global pass via LDS ---------
__global__ __launch_bounds__(256) void k_p4(
        const int* __restrict__ karr, const int* __restrict__ Ssum,
        int* __restrict__ row_ptr, int* __restrict__ edge_src, int n, int NB) {
    __shared__ int sb[257];
    __shared__ int cnt[256];
    __shared__ int curv[256];
    __shared__ int ebuf[8192];   // 32KB: bucket mean 4096, std ~64
    int c = blockIdx.x, t = threadIdx.x;
    int v = (t < NB) ? Ssum[t] : 0;
    int excl = block_excl_scan_256(v, nullptr);
    sb[t] = excl;
    if (t == 255) sb[256] = excl + v;
    cnt[t] = 0;
    __syncthreads();
    int lo = sb[c], hi = sb[c + 1];
    int ec = hi - lo;
    int nbuf = ec < 8192 ? ec : 8192;
    for (int i = t; i < nbuf; i += 256) {
        int p = karr[lo + i];
        ebuf[i] = p;
        atomicAdd(&cnt[p & 255], 1);
    }
    for (int i = 8192 + t; i < ec; i += 256)      // overflow path (theoretical)
        atomicAdd(&cnt[karr[lo + i] & 255], 1);
    __syncthreads();
    int excl2 = block_excl_scan_256(cnt[t], nullptr);
    int node = c * 256 + t;
    if (node < n) row_ptr[node] = lo + excl2;
    curv[t] = lo + excl2;
    __syncthreads();
    for (int i = t; i < nbuf; i += 256) {
        int p = ebuf[i];
        int pos = atomicAdd(&curv[p & 255], 1);   // LDS atomic
        edge_src[pos] = p >> 8;                    // top bits 0 (24-bit pack)
    }
    for (int i = 8192 + t; i < ec; i += 256) {
        int p = karr[lo + i];
        int pos = atomicAdd(&curv[p & 255], 1);
        edge_src[pos] = p >> 8;
    }
}

// ---------------- D6: fsfd layer 1 (h from global; fs stored FP16) -----------
__global__ __launch_bounds__(256) void k_fsfd(
        const float* __restrict__ h,
        const float* __restrict__ Ws, const float* __restrict__ bs,
        const float* __restrict__ Wd, const float* __restrict__ bd,
        __half* __restrict__ fs_h, float* __restrict__ fd, int n) {
    __shared__ float WsL[64 * 64];
    __shared__ float WdL[64 * 64];
    __shared__ float HL[64 * FSTR];
    {
        float4* s4 = (float4*)WsL; float4* d4 = (float4*)WdL;
        const float4* Ws4 = (const float4*)Ws; const float4* Wd4 = (const float4*)Wd;
#pragma unroll
        for (int r = 0; r < 4; ++r) {
            s4[r * 256 + threadIdx.x] = Ws4[r * 256 + threadIdx.x];
            d4[r * 256 + threadIdx.x] = Wd4[r * 256 + threadIdx.x];
        }
    }
    int node0 = blockIdx.x * 64;
    {
        const float4* g4 = (const float4*)(h + (size_t)node0 * 64);
        float4* h4 = (float4*)HL;
        int rows = n - node0; rows = rows < 64 ? rows : 64;
        int tn = threadIdx.x >> 4, tf = threadIdx.x & 15;
        if (rows == 64) {
#pragma unroll
            for (int r = 0; r < 4; ++r) {
                int nd = r * 16 + tn;
                h4[nd * (FSTR / 4) + tf] = g4[(size_t)nd * 16 + tf];
            }
        } else {
            int total = rows * 16;
            for (int i = threadIdx.x; i < total; i += 256)
                h4[(i / 16) * (FSTR / 4) + (i & 15)] = g4[i];
        }
    }
    __syncthreads();
    int ng = threadIdx.x >> 4;
    int cg = (threadIdx.x & 15) * 4;
    float4 bs4 = *(const float4*)(bs + cg);
    float4 bd4 = *(const float4*)(bd + cg);
    float4 aS[4], aD[4];
#pragma unroll
    for (int j = 0; j < 4; ++j) { aS[j] = bs4; aD[j] = bd4; }
#pragma unroll 4
    for (int k4 = 0; k4 < 16; ++k4) {
        float4 f[4];
#pragma unroll
        for (int j = 0; j < 4; ++j)
            f[j] = *(const float4*)(HL + (ng * 4 + j) * FSTR + k4 * 4);
        const float* sp = WsL + (k4 * 4) * 64 + cg;
        const float* dp = WdL + (k4 * 4) * 64 + cg;
        float4 s0 = *(const float4*)(sp);
        float4 s1 = *(const float4*)(sp + 64);
        float4 s2 = *(const float4*)(sp + 128);
        float4 s3 = *(const float4*)(sp + 192);
        float4 d0 = *(const float4*)(dp);
        float4 d1 = *(const float4*)(dp + 64);
        float4 d2 = *(const float4*)(dp + 128);
        float4 d3 = *(const float4*)(dp + 192);
#pragma unroll
        for (int j = 0; j < 4; ++j) {
            FMA_TILE(aS[j], f[j], s0, s1, s2, s3);
            FMA_TILE(aD[j], f[j], d0, d1, d2, d3);
        }
    }
#pragma unroll
    for (int j = 0; j < 4; ++j) {
        int node = node0 + ng * 4 + j;
        if (node < n) {
            *(uint2*)(fs_h + (size_t)node * 64 + cg) = f4_to_h4(aS[j]);
            *(float4*)(fd + (size_t)node * 64 + cg) = aD[j];
        }
    }
}

// ---------------- GATv2 aggregate common ----------------
__device__ __forceinline__ void edge_accum(float4 fv, float4 fdv, float4 a4,
                                           bool valid, float& ssum, float4& acc) {
    float tx = fv.x + fdv.x;
    float ty = fv.y + fdv.y;
    float tz = fv.z + fdv.z;
    float tw = fv.w + fdv.w;
    tx = fmaxf(tx, LRELU_SLOPE * tx);
    ty = fmaxf(ty, LRELU_SLOPE * ty);
    tz = fmaxf(tz, LRELU_SLOPE * tz);
    tw = fmaxf(tw, LRELU_SLOPE * tw);
    float s = tx * a4.x;
    s = fmaf(ty, a4.y, s);
    s = fmaf(tz, a4.z, s);
    s = fmaf(tw, a4.w, s);
    s = reduce_quad(s);
    float p = valid ? __expf(s) : 0.f;
    ssum += p;
    acc.x = fmaf(p, fv.x, acc.x);
    acc.y = fmaf(p, fv.y, acc.y);
    acc.z = fmaf(p, fv.z, acc.z);
    acc.w = fmaf(p, fv.w, acc.w);
}

// ---------------- D5: layer-0 aggregate, FP16 fs gather -> h (fp32) ----------
__global__ __launch_bounds__(256) void k_agg0_h(
        const __half* __restrict__ fs_h, const float4* __restrict__ fd4,
        const float4* __restrict__ attn4,
        const int* __restrict__ row_ptr, const int* __restrict__ edge_src,
        float4* __restrict__ hout4, int n) {
    int wid = threadIdx.x >> 6;
    int node = blockIdx.x * 4 + wid;
    if (node >= n) return;
    int lane = threadIdx.x & 63;
    int slot = lane >> 4;
    int sl   = lane & 15;
    float4 a4  = attn4[sl];
    float4 fdv = fd4[node * 16 + sl];
    int s0 = __builtin_amdgcn_readfirstlane(row_ptr[node]);
    int s1 = __builtin_amdgcn_readfirstlane(row_ptr[node + 1]);
    float4 acc = {0.f, 0.f, 0.f, 0.f};
    float ssum = 0.f;
    for (int base = s0; base < s1; base += 16) {
        int id[4];
#pragma unroll
        for (int k = 0; k < 4; ++k)
            id[k] = edge_src[base + k * 4 + slot];   // pad past E is zeroed
        uint2 raw[4];
#pragma unroll
        for (int k = 0; k < 4; ++k)
            raw[k] = *(const uint2*)(fs_h + (size_t)(unsigned)id[k] * 64 + sl * 4);
#pragma unroll
        for (int k = 0; k < 4; ++k)
            edge_accum(h4_to_f4(raw[k]), fdv, a4, base + k * 4 + slot < s1, ssum, acc);
    }
    acc.x += __shfl_xor(acc.x, 16); acc.x += __shfl_xor(acc.x, 32);
    acc.y += __shfl_xor(acc.y, 16); acc.y += __shfl_xor(acc.y, 32);
    acc.z += __shfl_xor(acc.z, 16); acc.z += __shfl_xor(acc.z, 32);
    acc.w += __shfl_xor(acc.w, 16); acc.w += __shfl_xor(acc.w, 32);
    ssum  += __shfl_xor(ssum, 16);  ssum  += __shfl_xor(ssum, 32);
    float inv = (s1 > s0) ? 1.f / ssum : 0.f;
    if (slot == 0) {
        float4 o;
        o.x = fmaxf(acc.x * inv, 0.f);
        o.y = fmaxf(acc.y * inv, 0.f);
        o.z = fmaxf(acc.z * inv, 0.f);
        o.w = fmaxf(acc.w * inv, 0.f);
        hout4[node * 16 + sl] = o;
    }
}

// ---------------- D7: layer-1 aggregate (FP16 gather) + output projection ----
__global__ __launch_bounds__(256) void k_agg_out(
        const __half* __restrict__ fs_h, const float4* __restrict__ fd4,
        const float4* __restrict__ attn4,
        const int* __restrict__ row_ptr, const int* __restrict__ edge_src,
        const float4* __restrict__ Wo4,
        const float* __restrict__ bo, float2* __restrict__ outp, int n) {
    int wid = threadIdx.x >> 6;
    int node = blockIdx.x * 4 + wid;
    if (node >= n) return;
    int lane = threadIdx.x & 63;
    int slot = lane >> 4;
    int sl   = lane & 15;
    float4 a4  = attn4[sl];
    float4 fdv = fd4[node * 16 + sl];
    int s0 = __builtin_amdgcn_readfirstlane(row_ptr[node]);
    int s1 = __builtin_amdgcn_readfirstlane(row_ptr[node + 1]);
    float4 acc = {0.f, 0.f, 0.f, 0.f};
    float ssum = 0.f;
    for (int base = s0; base < s1; base += 16) {
        int id[4];
#pragma unroll
        for (int k = 0; k < 4; ++k)
            id[k] = edge_src[base + k * 4 + slot];
        uint2 raw[4];
#pragma unroll
        for (int k = 0; k < 4; ++k)
            raw[k] = *(const uint2*)(fs_h + (size_t)(unsigned)id[k] * 64 + sl * 4);
#pragma unroll
        for (int k = 0; k < 4; ++k)
            edge_accum(h4_to_f4(raw[k]), fdv, a4, base + k * 4 + slot < s1, ssum, acc);
    }
    acc.x += __shfl_xor(acc.x, 16); acc.x += __shfl_xor(acc.x, 32);
    acc.y += __shfl_xor(acc.y, 16); acc.y += __shfl_xor(acc.y, 32);
    acc.z += __shfl_xor(acc.z, 16); acc.z += __shfl_xor(acc.z, 32);
    acc.w += __shfl_xor(acc.w, 16); acc.w += __shfl_xor(acc.w, 32);
    ssum  += __shfl_xor(ssum, 16);  ssum  += __shfl_xor(ssum, 32);
    float inv = (s1 > s0) ? 1.f / ssum : 0.f;
    float4 o;
    o.x = fmaxf(acc.x * inv, 0.f);
    o.y = fmaxf(acc.y * inv, 0.f);
    o.z = fmaxf(acc.z * inv, 0.f);
    o.w = fmaxf(acc.w * inv, 0.f);
    float4 wA = Wo4[sl * 2 + 0];
    float4 wB = Wo4[sl * 2 + 1];
    float c0 = o.x * wA.x + o.y * wA.z + o.z * wB.x + o.w * wB.z;
    float c1 = o.x * wA.y + o.y * wA.w + o.z * wB.y + o.w * wB.w;
    c0 = reduce16(c0);
    c1 = reduce16(c1);
    if (lane == 0) {
        float2 r; r.x = c0 + bo[0]; r.y = c1 + bo[1];
        outp[node] = r;
    }
}

extern "C" void kernel_launch(void* const* d_in, const int* in_sizes, int n_in,
                              void* d_out, int out_size, void* d_ws, size_t ws_size,
                              hipStream_t stream) {
    const float* feature  = (const float*)d_in[0];
    const int*   src      = (const int*)d_in[1];
    const int*   dst      = (const int*)d_in[2];
    const float* W_in     = (const float*)d_in[3];
    const float* b_in     = (const float*)d_in[4];
    const float* fc_src_W = (const float*)d_in[5];
    const float* fc_src_b = (const float*)d_in[6];
    const float* fc_dst_W = (const float*)d_in[7];
    const float* fc_dst_b = (const float*)d_in[8];
    const float* attn     = (const float*)d_in[9];
    const float* W_out    = (const float*)d_in[10];
    const float* b_out    = (const float*)d_in[11];

    const int N  = in_sizes[0] / 128;      // 50000
    const int E  = in_sizes[1];            // 800000
    const int B1 = (E + 4095) / 4096;      // 196 coarse blocks
    const int NB = (N + 255) / 256;        // 196 coarse buckets (dst>>8)

    char* ws = (char*)d_ws;
    size_t off = 0;
    auto take = [&](size_t bytes) { char* p = ws + off; off = (off + bytes + 255) & ~(size_t)255; return p; };
    int*    counts_T   = (int*)take((size_t)NB * B1 * 4);
    int*    off_T      = (int*)take((size_t)NB * B1 * 4);
    int*    Ssum       = (int*)take((size_t)256 * 4);
    int*    row_ptr    = (int*)take((size_t)(N + 1) * 4);
    int*    karr       = (int*)take((size_t)E * 4);
    int*    edge_src   = (int*)take((size_t)(E + 64) * 4);
    float*  h          = (float*)take((size_t)N * 64 * 4);
    float*  fd         = (float*)take((size_t)N * 64 * 4);
    __half* fs_h       = (__half*)take((size_t)N * 64 * 2);  // layer0 then layer1
    (void)ws_size; (void)n_in; (void)out_size;

    const int gemm_blocks = (N + 63) / 64;    // 782 (64 nodes/block)
    const int g_scan      = (NB + 3) / 4;     // 49 blocks = 196 scan waves
    const int agg_blocks  = (N + 3) / 4;

    // D1: hist || (gemm_in + fsfd layer0 fused; h stays in LDS; fs -> FP16)
    k_p1_fused<<<B1 + gemm_blocks, 256, 0, stream>>>(
        dst, counts_T, E, B1, NB,
        feature, W_in, b_in,
        fc_src_W, fc_src_b, fc_dst_W, fc_dst_b,
        fs_h, fd, N, gemm_blocks);

    // D2: parallel coarse scan
    k_scan<<<g_scan, 256, 0, stream>>>(counts_T, off_T, Ssum, row_ptr,
                                       edge_src, E, B1, NB, N);

    // D3: partition edges into coarse buckets (packed 24-bit records)
    k_p3<<<B1, 256, 0, stream>>>(src, dst, off_T, Ssum, karr, E, B1, NB);

    // D4: fine counting sort within buckets -> row_ptr + edge_src
    k_p4<<<NB, 256, 0, stream>>>(karr, Ssum, row_ptr, edge_src, N, NB);

    // D5: layer 0 aggregate (FP16 gather) -> h
    k_agg0_h<<<agg_blocks, 256, 0, stream>>>(
        fs_h, (const float4*)fd, (const float4*)attn,
        row_ptr, edge_src, (float4*)h, N);

    // D6: layer 1 projections (fs -> FP16, fd FP32)
    k_fsfd<<<gemm_blocks, 256, 0, stream>>>(h, fc_src_W + 4096, fc_src_b + 64,
                                            fc_dst_W + 4096, fc_dst_b + 64, fs_h, fd, N);

    // D7: layer 1 aggregate (FP16 gather) + output projection fused
    k_agg_out<<<agg_blocks, 256, 0, stream>>>(
        fs_h, (const float4*)fd, (const float4*)(attn + 64),
        row_ptr, edge_src, (const float4*)W_out, b_out, (float2*)d_out, N);
}

// Round 16
// 231.388 us; speedup vs baseline: 1.0268x; 1.0268x over previous
//
#include <hip/hip_runtime.h>
#include <hip/hip_fp16.h>

#define LRELU_SLOPE 0.2f
#define FSTR 68   // padded LDS row stride in floats (64+4)

// ---------------- DPP helpers ----------------
template <int CTRL>
__device__ __forceinline__ float dpp_add(float x) {
    int xi = __float_as_int(x);
    int yi = __builtin_amdgcn_update_dpp(xi, xi, CTRL, 0xF, 0xF, false);
    return x + __int_as_float(yi);
}
__device__ __forceinline__ float reduce16(float t) {
    t = dpp_add<0x128>(t);  // row_ror:8
    t = dpp_add<0x124>(t);  // row_ror:4
    t = dpp_add<0x122>(t);  // row_ror:2
    t = dpp_add<0x121>(t);  // row_ror:1
    return t;
}
__device__ __forceinline__ float reduce_quad(float t) {
    t = dpp_add<0xB1>(t);   // quad_perm [1,0,3,2]
    t = dpp_add<0x4E>(t);   // quad_perm [2,3,0,1]
    return t;
}

__device__ __forceinline__ float4 h4_to_f4(uint2 raw) {
    __half2 h0 = *(__half2*)&raw.x;
    __half2 h1 = *(__half2*)&raw.y;
    float2 a = __half22float2(h0);
    float2 b = __half22float2(h1);
    return make_float4(a.x, a.y, b.x, b.y);
}
__device__ __forceinline__ uint2 f4_to_h4(float4 v) {
    union { __half2 h2[2]; uint2 u; } pk;
    pk.h2[0] = __floats2half2_rn(v.x, v.y);
    pk.h2[1] = __floats2half2_rn(v.z, v.w);
    return pk.u;
}

// ---------------- block-wide exclusive scan helper (256 threads) -------------
__device__ __forceinline__ int block_excl_scan_256(int v, int* block_total) {
    int lane = threadIdx.x & 63;
    int wid  = threadIdx.x >> 6;
    int x = v;
#pragma unroll
    for (int off = 1; off < 64; off <<= 1) {
        int y = __shfl_up(x, off, 64);
        if (lane >= off) x += y;
    }
    __shared__ int wsum[4];
    if (lane == 63) wsum[wid] = x;
    __syncthreads();
    int t0 = wsum[0], t1 = wsum[1], t2 = wsum[2], t3 = wsum[3];
    int wofs = (wid > 0 ? t0 : 0) + (wid > 1 ? t1 : 0) + (wid > 2 ? t2 : 0);
    if (block_total) *block_total = t0 + t1 + t2 + t3;
    return wofs + x - v;  // exclusive
}

// role split for fused kernels: interleave A/B blocks by parity
__device__ __forceinline__ void role_split(int bid, int gA, int gB, bool& isA, int& idx) {
    int m = (gA < gB ? gA : gB) * 2;
    if (bid < m) { isA = (bid & 1) == 0; idx = bid >> 1; }
    else         { isA = (gA > gB);      idx = (m >> 1) + (bid - m); }
}

#define FMA_TILE(accv, fv, w0, w1, w2, w3)                                     \
    accv.x += fv.x * w0.x + fv.y * w1.x + fv.z * w2.x + fv.w * w3.x;           \
    accv.y += fv.x * w0.y + fv.y * w1.y + fv.z * w2.y + fv.w * w3.y;           \
    accv.z += fv.x * w0.z + fv.y * w1.z + fv.z * w2.z + fv.w * w3.z;           \
    accv.w += fv.x * w0.w + fv.y * w1.w + fv.z * w2.w + fv.w * w3.w;

// ---------------- D1: hist  ||  (gemm_in + fsfd layer0 fused, h in LDS) ------
// r12/r14 structure (52 VGPR, no spill): fp32 FL, W staged in 16KB halves.
// LDS = 16K(WL) + 17.4K(FL) + 1K(hist) = 34.8KB -> 4 blocks/CU.
// fp16 ONLY at the final fs0 global store (not in the FMA path — r13 spilled;
// r15's register prefetch of features was neutral-negative — reverted).
__global__ __launch_bounds__(256) void k_p1_fused(
        const int* __restrict__ dst, int* __restrict__ counts_T, int E, int B1, int NB,
        const float* __restrict__ feat, const float* __restrict__ Win,
        const float* __restrict__ bin,
        const float* __restrict__ Ws0, const float* __restrict__ bs0,
        const float* __restrict__ Wd0, const float* __restrict__ bd0,
        __half* __restrict__ fs_h, float* __restrict__ fd, int n, int g_gemm) {
    __shared__ float WL[64 * 64];         // 16KB: Win half / Ws0 / Wd0
    __shared__ float FL[64 * FSTR];       // feature k-half, later h-tile
    __shared__ int hist[256];
    bool isA; int idx;
    role_split(blockIdx.x, B1, g_gemm, isA, idx);
    if (isA) {
        hist[threadIdx.x] = 0;
        __syncthreads();
        int base = idx * 4096;
        if (base + 4096 <= E) {
            const int4* d4 = (const int4*)(dst + base);
#pragma unroll
            for (int it = 0; it < 4; ++it) {
                int4 q = d4[it * 256 + threadIdx.x];
                atomicAdd(&hist[q.x >> 8], 1);
                atomicAdd(&hist[q.y >> 8], 1);
                atomicAdd(&hist[q.z >> 8], 1);
                atomicAdd(&hist[q.w >> 8], 1);
            }
        } else {
            for (int it = 0; it < 16; ++it) {
                int e = base + it * 256 + threadIdx.x;
                if (e < E) atomicAdd(&hist[dst[e] >> 8], 1);
            }
        }
        __syncthreads();
        if (threadIdx.x < NB) counts_T[threadIdx.x * B1 + idx] = hist[threadIdx.x];
        return;
    }
    int node0 = idx * 64;
    int rows = n - node0; rows = rows < 64 ? rows : 64;
    int ng = threadIdx.x >> 4;        // 0..15 node group
    int cg = (threadIdx.x & 15) * 4;  // col base
    int tn = threadIdx.x >> 4, tf = threadIdx.x & 15;
    float4 acc[4];
    {
        float4 bb = *(const float4*)(bin + cg);
#pragma unroll
        for (int j = 0; j < 4; ++j) acc[j] = bb;
    }
    // ---- phase 1: gemm_in, two k-halves (features AND W_in staged per half) --
#pragma unroll
    for (int hk = 0; hk < 2; ++hk) {
        {   // stage features (64x64 k-half, padded rows) + W_in half (16KB)
            const float4* g4 = (const float4*)(feat + (size_t)node0 * 128 + hk * 64);
            float4* f4 = (float4*)FL;
#pragma unroll
            for (int r = 0; r < 4; ++r) {
                int nd = r * 16 + tn;
                if (nd < rows) f4[nd * (FSTR / 4) + tf] = g4[(size_t)nd * 32 + tf];
            }
            float4* WL4 = (float4*)WL;
            const float4* W4 = (const float4*)(Win + hk * 4096);
#pragma unroll
            for (int r = 0; r < 4; ++r)
                WL4[r * 256 + threadIdx.x] = W4[r * 256 + threadIdx.x];
        }
        __syncthreads();
#pragma unroll 4
        for (int k4 = 0; k4 < 16; ++k4) {
            float4 f[4];
#pragma unroll
            for (int j = 0; j < 4; ++j)
                f[j] = *(const float4*)(FL + (ng * 4 + j) * FSTR + k4 * 4);
            const float* wp = WL + (k4 * 4) * 64 + cg;
            float4 w0 = *(const float4*)(wp);
            float4 w1 = *(const float4*)(wp + 64);
            float4 w2 = *(const float4*)(wp + 128);
            float4 w3 = *(const float4*)(wp + 192);
#pragma unroll
            for (int j = 0; j < 4; ++j) { FMA_TILE(acc[j], f[j], w0, w1, w2, w3); }
        }
        __syncthreads();  // FL/WL reads done before restage
    }
    // ---- phase 2a: h-tile -> FL; Ws0 -> WL; compute fs0 (store FP16) ---------
#pragma unroll
    for (int j = 0; j < 4; ++j)
        *(float4*)(FL + (ng * 4 + j) * FSTR + cg) = acc[j];
    {
        float4* WL4 = (float4*)WL;
        const float4* W4 = (const float4*)Ws0;
#pragma unroll
        for (int r = 0; r < 4; ++r)
            WL4[r * 256 + threadIdx.x] = W4[r * 256 + threadIdx.x];
    }
    __syncthreads();
    {
        float4 bs4 = *(const float4*)(bs0 + cg);
        float4 aS[4];
#pragma unroll
        for (int j = 0; j < 4; ++j) aS[j] = bs4;
#pragma unroll 4
        for (int k4 = 0; k4 < 16; ++k4) {
            float4 f[4];
#pragma unroll
            for (int j = 0; j < 4; ++j)
                f[j] = *(const float4*)(FL + (ng * 4 + j) * FSTR + k4 * 4);
            const float* wp = WL + (k4 * 4) * 64 + cg;
            float4 w0 = *(const float4*)(wp);
            float4 w1 = *(const float4*)(wp + 64);
            float4 w2 = *(const float4*)(wp + 128);
            float4 w3 = *(const float4*)(wp + 192);
#pragma unroll
            for (int j = 0; j < 4; ++j) { FMA_TILE(aS[j], f[j], w0, w1, w2, w3); }
        }
#pragma unroll
        for (int j = 0; j < 4; ++j) {
            int node = node0 + ng * 4 + j;
            if (node < n)
                *(uint2*)(fs_h + (size_t)node * 64 + cg) = f4_to_h4(aS[j]);
        }
    }
    __syncthreads();
    // ---- phase 2b: Wd0 -> WL; compute fd (FP32) -----------------------------
    {
        float4* WL4 = (float4*)WL;
        const float4* W4 = (const float4*)Wd0;
#pragma unroll
        for (int r = 0; r < 4; ++r)
            WL4[r * 256 + threadIdx.x] = W4[r * 256 + threadIdx.x];
    }
    __syncthreads();
    {
        float4 bd4 = *(const float4*)(bd0 + cg);
        float4 aD[4];
#pragma unroll
        for (int j = 0; j < 4; ++j) aD[j] = bd4;
#pragma unroll 4
        for (int k4 = 0; k4 < 16; ++k4) {
            float4 f[4];
#pragma unroll
            for (int j = 0; j < 4; ++j)
                f[j] = *(const float4*)(FL + (ng * 4 + j) * FSTR + k4 * 4);
            const float* wp = WL + (k4 * 4) * 64 + cg;
            float4 w0 = *(const float4*)(wp);
            float4 w1 = *(const float4*)(wp + 64);
            float4 w2 = *(const float4*)(wp + 128);
            float4 w3 = *(const float4*)(wp + 192);
#pragma unroll
            for (int j = 0; j < 4; ++j) { FMA_TILE(aD[j], f[j], w0, w1, w2, w3); }
        }
#pragma unroll
        for (int j = 0; j < 4; ++j) {
            int node = node0 + ng * 4 + j;
            if (node < n) *(float4*)(fd + (size_t)node * 64 + cg) = aD[j];
        }
    }
}

// ---------------- D2: parallel coarse scan ----------------
__global__ __launch_bounds__(256) void k_scan(
        const int* __restrict__ counts_T, int* __restrict__ off_T,
        int* __restrict__ Ssum, int* __restrict__ row_ptr,
        int* __restrict__ edge_src, int E, int B1, int NB, int n_nodes) {
    int c = blockIdx.x * 4 + (threadIdx.x >> 6);
    int lane = threadIdx.x & 63;
    if (c < NB) {
        int carry = 0;
        for (int b0 = 0; b0 < B1; b0 += 64) {
            int b = b0 + lane;
            int v = (b < B1) ? counts_T[c * B1 + b] : 0;
            int x = v;
#pragma unroll
            for (int o = 1; o < 64; o <<= 1) {
                int y = __shfl_up(x, o, 64);
                if (lane >= o) x += y;
            }
            if (b < B1) off_T[c * B1 + b] = carry + x - v;
            carry += __shfl(x, 63, 64);
        }
        if (lane == 0) Ssum[c] = carry;
    }
    if (blockIdx.x == 0) {
        if (threadIdx.x < 64) edge_src[E + threadIdx.x] = 0;  // pad for k_agg
        if (threadIdx.x == 0) row_ptr[n_nodes] = E;
    }
}

// ---------------- D3: coarse partition, packed 24-bit (src<<8)|fine ----------
__global__ __launch_bounds__(256) void k_p3(
        const int* __restrict__ src, const int* __restrict__ dst,
        const int* __restrict__ off_T, const int* __restrict__ Ssum,
        int* __restrict__ karr, int E, int B1, int NB) {
    __shared__ int cur[256];
    int b = blockIdx.x, t = threadIdx.x;
    int v = (t < NB) ? Ssum[t] : 0;
    int base_t = block_excl_scan_256(v, nullptr);   // bucket_base[t]
    cur[t] = (t < NB) ? base_t + off_T[t * B1 + b] : 0;
    __syncthreads();
    int base = b * 4096;
    if (base + 4096 <= E) {
        const int4* d4 = (const int4*)(dst + base);
        const int4* s4 = (const int4*)(src + base);
#pragma unroll
        for (int it = 0; it < 4; ++it) {
            int4 qd = d4[it * 256 + t];
            int4 qs = s4[it * 256 + t];
            int pos;
            pos = atomicAdd(&cur[qd.x >> 8], 1); karr[pos] = (qs.x << 8) | (qd.x & 255);
            pos = atomicAdd(&cur[qd.y >> 8], 1); karr[pos] = (qs.y << 8) | (qd.y & 255);
            pos = atomicAdd(&cur[qd.z >> 8], 1); karr[pos] = (qs.z << 8) | (qd.z & 255);
            pos = atomicAdd(&cur[qd.w >> 8], 1); karr[pos] = (qs.w << 8) | (qd.w & 255);
        }
    } else {
        for (int it = 0; it < 16; ++it) {
            int e = base + it * 256 + t;
            if (e < E) {
                int d = dst[e], s = src[e];
                int pos = atomicAdd(&cur[d >> 8], 1);  // LDS atomic
                karr[pos] = (s << 8) | (d & 255);
            }
        }
    }
}

// ---------------- D4: fine counting sort, single global pass via LDS ---------
__global__ __launch_bounds__(256) void k_p4(
        const int* __restrict__ karr, const int* __restrict__ Ssum,
        int* __restrict__ row_ptr, int* __restrict__ edge_src, int n, int NB) {
    __shared__ int sb[257];
    __shared__ int cnt[256];
    __shared__ int curv[256];
    __shared__ int ebuf[8192];   // 32KB: bucket mean 4096, std ~64
    int c = blockIdx.x, t = threadIdx.x;
    int v = (t < NB) ? Ssum[t] : 0;
    int excl = block_excl_scan_256(v, nullptr);
    sb[t] = excl;
    if (t == 255) sb[256] = excl + v;
    cnt[t] = 0;
    __syncthreads();
    int lo = sb[c], hi = sb[c + 1];
    int ec = hi - lo;
    int nbuf = ec < 8192 ? ec : 8192;
    for (int i = t; i < nbuf; i += 256) {
        int p = karr[lo + i];
        ebuf[i] = p;
        atomicAdd(&cnt[p & 255], 1);
    }
    for (int i = 8192 + t; i < ec; i += 256)      // overflow path (theoretical)
        atomicAdd(&cnt[karr[lo + i] & 255], 1);
    __syncthreads();
    int excl2 = block_excl_scan_256(cnt[t], nullptr);
    int node = c * 256 + t;
    if (node < n) row_ptr[node] = lo + excl2;
    curv[t] = lo + excl2;
    __syncthreads();
    for (int i = t; i < nbuf; i += 256) {
        int p = ebuf[i];
        int pos = atomicAdd(&curv[p & 255], 1);   // LDS atomic
        edge_src[pos] = p >> 8;                    // top bits 0 (24-bit pack)
    }
    for (int i = 8192 + t; i < ec; i += 256) {
        int p = karr[lo + i];
        int pos = atomicAdd(&curv[p & 255], 1);
        edge_src[pos] = p >> 8;
    }
}

// ---------------- D6: fsfd layer 1 (h from global; fs stored FP16) -----------
__global__ __launch_bounds__(256) void k_fsfd(
        const float* __restrict__ h,
        const float* __restrict__ Ws, const float* __restrict__ bs,
        const float* __restrict__ Wd, const float* __restrict__ bd,
        __half* __restrict__ fs_h, float* __restrict__ fd, int n) {
    __shared__ float WsL[64 * 64];
    __shared__ float WdL[64 * 64];
    __shared__ float HL[64 * FSTR];
    {
        float4* s4 = (float4*)WsL; float4* d4 = (float4*)WdL;
        const float4* Ws4 = (const float4*)Ws; const float4* Wd4 = (const float4*)Wd;
#pragma unroll
        for (int r = 0; r < 4; ++r) {
            s4[r * 256 + threadIdx.x] = Ws4[r * 256 + threadIdx.x];
            d4[r * 256 + threadIdx.x] = Wd4[r * 256 + threadIdx.x];
        }
    }
    int node0 = blockIdx.x * 64;
    {
        const float4* g4 = (const float4*)(h + (size_t)node0 * 64);
        float4* h4 = (float4*)HL;
        int rows = n - node0; rows = rows < 64 ? rows : 64;
        int tn = threadIdx.x >> 4, tf = threadIdx.x & 15;
        if (rows == 64) {
#pragma unroll
            for (int r = 0; r < 4; ++r) {
                int nd = r * 16 + tn;
                h4[nd * (FSTR / 4) + tf] = g4[(size_t)nd * 16 + tf];
            }
        } else {
            int total = rows * 16;
            for (int i = threadIdx.x; i < total; i += 256)
                h4[(i / 16) * (FSTR / 4) + (i & 15)] = g4[i];
        }
    }
    __syncthreads();
    int ng = threadIdx.x >> 4;
    int cg = (threadIdx.x & 15) * 4;
    float4 bs4 = *(const float4*)(bs + cg);
    float4 bd4 = *(const float4*)(bd + cg);
    float4 aS[4], aD[4];
#pragma unroll
    for (int j = 0; j < 4; ++j) { aS[j] = bs4; aD[j] = bd4; }
#pragma unroll 4
    for (int k4 = 0; k4 < 16; ++k4) {
        float4 f[4];
#pragma unroll
        for (int j = 0; j < 4; ++j)
            f[j] = *(const float4*)(HL + (ng * 4 + j) * FSTR + k4 * 4);
        const float* sp = WsL + (k4 * 4) * 64 + cg;
        const float* dp = WdL + (k4 * 4) * 64 + cg;
        float4 s0 = *(const float4*)(sp);
        float4 s1 = *(const float4*)(sp + 64);
        float4 s2 = *(const float4*)(sp + 128);
        float4 s3 = *(const float4*)(sp + 192);
        float4 d0 = *(const float4*)(dp);
        float4 d1 = *(const float4*)(dp + 64);
        float4 d2 = *(const float4*)(dp + 128);
        float4 d3 = *(const float4*)(dp + 192);
#pragma unroll
        for (int j = 0; j < 4; ++j) {
            FMA_TILE(aS[j], f[j], s0, s1, s2, s3);
            FMA_TILE(aD[j], f[j], d0, d1, d2, d3);
        }
    }
#pragma unroll
    for (int j = 0; j < 4; ++j) {
        int node = node0 + ng * 4 + j;
        if (node < n) {
            *(uint2*)(fs_h + (size_t)node * 64 + cg) = f4_to_h4(aS[j]);
            *(float4*)(fd + (size_t)node * 64 + cg) = aD[j];
        }
    }
}

// ---------------- GATv2 aggregate common ----------------
__device__ __forceinline__ void edge_accum(float4 fv, float4 fdv, float4 a4,
                                           bool valid, float& ssum, float4& acc) {
    float tx = fv.x + fdv.x;
    float ty = fv.y + fdv.y;
    float tz = fv.z + fdv.z;
    float tw = fv.w + fdv.w;
    tx = fmaxf(tx, LRELU_SLOPE * tx);
    ty = fmaxf(ty, LRELU_SLOPE * ty);
    tz = fmaxf(tz, LRELU_SLOPE * tz);
    tw = fmaxf(tw, LRELU_SLOPE * tw);
    float s = tx * a4.x;
    s = fmaf(ty, a4.y, s);
    s = fmaf(tz, a4.z, s);
    s = fmaf(tw, a4.w, s);
    s = reduce_quad(s);
    float p = valid ? __expf(s) : 0.f;
    ssum += p;
    acc.x = fmaf(p, fv.x, acc.x);
    acc.y = fmaf(p, fv.y, acc.y);
    acc.z = fmaf(p, fv.z, acc.z);
    acc.w = fmaf(p, fv.w, acc.w);
}

// ---------------- D5: layer-0 aggregate, FP16 fs gather -> h (fp32) ----------
__global__ __launch_bounds__(256) void k_agg0_h(
        const __half* __restrict__ fs_h, const float4* __restrict__ fd4,
        const float4* __restrict__ attn4,
        const int* __restrict__ row_ptr, const int* __restrict__ edge_src,
        float4* __restrict__ hout4, int n) {
    int wid = threadIdx.x >> 6;
    int node = blockIdx.x * 4 + wid;
    if (node >= n) return;
    int lane = threadIdx.x & 63;
    int slot = lane >> 4;
    int sl   = lane & 15;
    float4 a4  = attn4[sl];
    float4 fdv = fd4[node * 16 + sl];
    int s0 = __builtin_amdgcn_readfirstlane(row_ptr[node]);
    int s1 = __builtin_amdgcn_readfirstlane(row_ptr[node + 1]);
    float4 acc = {0.f, 0.f, 0.f, 0.f};
    float ssum = 0.f;
    for (int base = s0; base < s1; base += 16) {
        int id[4];
#pragma unroll
        for (int k = 0; k < 4; ++k)
            id[k] = edge_src[base + k * 4 + slot];   // pad past E is zeroed
        uint2 raw[4];
#pragma unroll
        for (int k = 0; k < 4; ++k)
            raw[k] = *(const uint2*)(fs_h + (size_t)(unsigned)id[k] * 64 + sl * 4);
#pragma unroll
        for (int k = 0; k < 4; ++k)
            edge_accum(h4_to_f4(raw[k]), fdv, a4, base + k * 4 + slot < s1, ssum, acc);
    }
    acc.x += __shfl_xor(acc.x, 16); acc.x += __shfl_xor(acc.x, 32);
    acc.y += __shfl_xor(acc.y, 16); acc.y += __shfl_xor(acc.y, 32);
    acc.z += __shfl_xor(acc.z, 16); acc.z += __shfl_xor(acc.z, 32);
    acc.w += __shfl_xor(acc.w, 16); acc.w += __shfl_xor(acc.w, 32);
    ssum  += __shfl_xor(ssum, 16);  ssum  += __shfl_xor(ssum, 32);
    float inv = (s1 > s0) ? 1.f / ssum : 0.f;
    if (slot == 0) {
        float4 o;
        o.x = fmaxf(acc.x * inv, 0.f);
        o.y = fmaxf(acc.y * inv, 0.f);
        o.z = fmaxf(acc.z * inv, 0.f);
        o.w = fmaxf(acc.w * inv, 0.f);
        hout4[node * 16 + sl] = o;
    }
}

// ---------------- D7: layer-1 aggregate (FP16 gather) + output projection ----
__global__ __launch_bounds__(256) void k_agg_out(
        const __half* __restrict__ fs_h, const float4* __restrict__ fd4,
        const float4* __restrict__ attn4,
        const int* __restrict__ row_ptr, const int* __restrict__ edge_src,
        const float4* __restrict__ Wo4,
        const float* __restrict__ bo, float2* __restrict__ outp, int n) {
    int wid = threadIdx.x >> 6;
    int node = blockIdx.x * 4 + wid;
    if (node >= n) return;
    int lane = threadIdx.x & 63;
    int slot = lane >> 4;
    int sl   = lane & 15;
    float4 a4  = attn4[sl];
    float4 fdv = fd4[node * 16 + sl];
    int s0 = __builtin_amdgcn_readfirstlane(row_ptr[node]);
    int s1 = __builtin_amdgcn_readfirstlane(row_ptr[node + 1]);
    float4 acc = {0.f, 0.f, 0.f, 0.f};
    float ssum = 0.f;
    for (int base = s0; base < s1; base += 16) {
        int id[4];
#pragma unroll
        for (int k = 0; k < 4; ++k)
            id[k] = edge_src[base + k * 4 + slot];
        uint2 raw[4];
#pragma unroll
        for (int k = 0; k < 4; ++k)
            raw[k] = *(const uint2*)(fs_h + (size_t)(unsigned)id[k] * 64 + sl * 4);
#pragma unroll
        for (int k = 0; k < 4; ++k)
            edge_accum(h4_to_f4(raw[k]), fdv, a4, base + k * 4 + slot < s1, ssum, acc);
    }
    acc.x += __shfl_xor(acc.x, 16); acc.x += __shfl_xor(acc.x, 32);
    acc.y += __shfl_xor(acc.y, 16); acc.y += __shfl_xor(acc.y, 32);
    acc.z += __shfl_xor(acc.z, 16); acc.z += __shfl_xor(acc.z, 32);
    acc.w += __shfl_xor(acc.w, 16); acc.w += __shfl_xor(acc.w, 32);
    ssum  += __shfl_xor(ssum, 16);  ssum  += __shfl_xor(ssum, 32);
    float inv = (s1 > s0) ? 1.f / ssum : 0.f;
    float4 o;
    o.x = fmaxf(acc.x * inv, 0.f);
    o.y = fmaxf(acc.y * inv, 0.f);
    o.z = fmaxf(acc.z * inv, 0.f);
    o.w = fmaxf(acc.w * inv, 0.f);
    float4 wA = Wo4[sl * 2 + 0];
    float4 wB = Wo4[sl * 2 + 1];
    float c0 = o.x * wA.x + o.y * wA.z + o.z * wB.x + o.w * wB.z;
    float c1 = o.x * wA.y + o.y * wA.w + o.z * wB.y + o.w * wB.w;
    c0 = reduce16(c0);
    c1 = reduce16(c1);
    if (lane == 0) {
        float2 r; r.x = c0 + bo[0]; r.y = c1 + bo[1];
        outp[node] = r;
    }
}

extern "C" void kernel_launch(void* const* d_in, const int* in_sizes, int n_in,
                              void* d_out, int out_size, void* d_ws, size_t ws_size,
                              hipStream_t stream) {
    const float* feature  = (const float*)d_in[0];
    const int*   src      = (const int*)d_in[1];
    const int*   dst      = (const int*)d_in[2];
    const float* W_in     = (const float*)d_in[3];
    const float* b_in     = (const float*)d_in[4];
    const float* fc_src_W = (const float*)d_in[5];
    const float* fc_src_b = (const float*)d_in[6];
    const float* fc_dst_W = (const float*)d_in[7];
    const float* fc_dst_b = (const float*)d_in[8];
    const float* attn     = (const float*)d_in[9];
    const float* W_out    = (const float*)d_in[10];
    const float* b_out    = (const float*)d_in[11];

    const int N  = in_sizes[0] / 128;      // 50000
    const int E  = in_sizes[1];            // 800000
    const int B1 = (E + 4095) / 4096;      // 196 coarse blocks
    const int NB = (N + 255) / 256;        // 196 coarse buckets (dst>>8)

    char* ws = (char*)d_ws;
    size_t off = 0;
    auto take = [&](size_t bytes) { char* p = ws + off; off = (off + bytes + 255) & ~(size_t)255; return p; };
    int*    counts_T   = (int*)take((size_t)NB * B1 * 4);
    int*    off_T      = (int*)take((size_t)NB * B1 * 4);
    int*    Ssum       = (int*)take((size_t)256 * 4);
    int*    row_ptr    = (int*)take((size_t)(N + 1) * 4);
    int*    karr       = (int*)take((size_t)E * 4);
    int*    edge_src   = (int*)take((size_t)(E + 64) * 4);
    float*  h          = (float*)take((size_t)N * 64 * 4);
    float*  fd         = (float*)take((size_t)N * 64 * 4);
    __half* fs_h       = (__half*)take((size_t)N * 64 * 2);  // layer0 then layer1
    (void)ws_size; (void)n_in; (void)out_size;

    const int gemm_blocks = (N + 63) / 64;    // 782 (64 nodes/block)
    const int g_scan      = (NB + 3) / 4;     // 49 blocks = 196 scan waves
    const int agg_blocks  = (N + 3) / 4;

    // D1: hist || (gemm_in + fsfd layer0 fused; h stays in LDS; fs -> FP16)
    k_p1_fused<<<B1 + gemm_blocks, 256, 0, stream>>>(
        dst, counts_T, E, B1, NB,
        feature, W_in, b_in,
        fc_src_W, fc_src_b, fc_dst_W, fc_dst_b,
        fs_h, fd, N, gemm_blocks);

    // D2: parallel coarse scan
    k_scan<<<g_scan, 256, 0, stream>>>(counts_T, off_T, Ssum, row_ptr,
                                       edge_src, E, B1, NB, N);

    // D3: partition edges into coarse buckets (packed 24-bit records)
    k_p3<<<B1, 256, 0, stream>>>(src, dst, off_T, Ssum, karr, E, B1, NB);

    // D4: fine counting sort within buckets -> row_ptr + edge_src
    k_p4<<<NB, 256, 0, stream>>>(karr, Ssum, row_ptr, edge_src, N, NB);

    // D5: layer 0 aggregate (FP16 gather) -> h
    k_agg0_h<<<agg_blocks, 256, 0, stream>>>(
        fs_h, (const float4*)fd, (const float4*)attn,
        row_ptr, edge_src, (float4*)h, N);

    // D6: layer 1 projections (fs -> FP16, fd FP32)
    k_fsfd<<<gemm_blocks, 256, 0, stream>>>(h, fc_src_W + 4096, fc_src_b + 64,
                                            fc_dst_W + 4096, fc_dst_b + 64, fs_h, fd, N);

    // D7: layer 1 aggregate (FP16 gather) + output projection fused
    k_agg_out<<<agg_blocks, 256, 0, stream>>>(
        fs_h, (const float4*)fd, (const float4*)(attn + 64),
        row_ptr, edge_src, (const float4*)W_out, b_out, (float2*)d_out, N);
}